// Round 6
// baseline (328.225 us; speedup 1.0000x reference)
//
#include <hip/hip_runtime.h>

typedef _Float16 f16x8 __attribute__((ext_vector_type(8)));
typedef float f32x4 __attribute__((ext_vector_type(4)));

#define NN 65536
#define KK 2048
#define DD 64

__device__ __forceinline__ unsigned int fkey(float f) {
  unsigned int u = __float_as_uint(f);
  return (u & 0x80000000u) ? ~u : (u | 0x80000000u);
}

// --- K1: normalize codebook -> cbT32[64][2048], cn2[2048], fp16-split frags ---
// B' frag layout (f16 units): idx = s*65536 + c*32 + g2*8 + i   (s=k>>5, g2=(k>>3)&3, i=k&7)
__global__ void k_norm_cb(const float* __restrict__ cb, float* __restrict__ cbT32,
                          float* __restrict__ cn2,
                          unsigned short* __restrict__ Bhi,
                          unsigned short* __restrict__ Blo) {
  int gid = blockIdx.x * blockDim.x + threadIdx.x;
  int c = gid >> 6;   // codebook row, one wave per row
  int k = gid & 63;   // dim
  float v = cb[c * DD + k];
  float ss = v * v;
  #pragma unroll
  for (int o = 32; o; o >>= 1) ss += __shfl_xor(ss, o);
  float inv = 1.0f / fmaxf(sqrtf(ss), 1e-12f);
  float cn = v * inv;
  cbT32[k * KK + c] = cn;
  float s2 = cn * cn;
  #pragma unroll
  for (int o = 32; o; o >>= 1) s2 += __shfl_xor(s2, o);
  if (k == 0) cn2[c] = s2;
  // fp16 split: cn*256 = hh + hl/4096  (both fp16-normal ranged)
  float sh = cn * 256.0f;
  _Float16 hh = (_Float16)sh;
  float resid = sh - (float)hh;
  _Float16 hl = (_Float16)(resid * 4096.0f);
  int s = k >> 5, g2 = (k >> 3) & 3, i = k & 7;
  int idx = s * 65536 + c * 32 + g2 * 8 + i;
  Bhi[idx] = *(unsigned short*)&hh;
  Blo[idx] = *(unsigned short*)&hl;
}

// --- K2: normalize z rows -> fp16-split A frags ---
// A' frag layout (f16x8 units): idx = (rt*2+s)*64 + g2*16 + r
__global__ void k_norm_z(const float* __restrict__ z,
                         unsigned short* __restrict__ Ahi,
                         unsigned short* __restrict__ Alo) {
  __shared__ float np_[8][32];
  __shared__ float invS[32];
  int t = threadIdx.x;
  int r32 = t & 31, q = t >> 5;  // row-in-32, k-chunk (8 k each)
  int n0 = blockIdx.x * 32;
  int w0 = n0 & 63, hh = (n0 >> 6) & 63, bb = n0 >> 12;
  const float* src = z + (size_t)bb * 262144 + (size_t)q * 8 * 4096 + hh * 64 + w0 + r32;
  float v[8];
  float ss = 0.f;
  #pragma unroll
  for (int i = 0; i < 8; ++i) {
    float x = src[(size_t)i * 4096];
    v[i] = x;
    ss = fmaf(x, x, ss);
  }
  np_[q][r32] = ss;
  __syncthreads();
  if (t < 32) {
    float s = 0.f;
    #pragma unroll
    for (int qq = 0; qq < 8; ++qq) s += np_[qq][t];
    invS[t] = 1.0f / fmaxf(sqrtf(s), 1e-12f);
  }
  __syncthreads();
  float inv = invS[r32] * 256.0f;
  union { _Float16 h[8]; uint4 u; } hi, lo;
  #pragma unroll
  for (int i = 0; i < 8; ++i) {
    float sh = v[i] * inv;
    _Float16 a = (_Float16)sh;
    hi.h[i] = a;
    lo.h[i] = (_Float16)((sh - (float)a) * 4096.0f);
  }
  int rt = (n0 + r32) >> 4;
  int r = r32 & 15;
  int s = q >> 2, g2 = q & 3;
  size_t idx = (size_t)(rt * 2 + s) * 64 + g2 * 16 + r;
  ((uint4*)Ahi)[idx] = hi.u;
  ((uint4*)Alo)[idx] = lo.u;
}

// --- K3: MFMA GEMM + argmin + softmax + prob/q + loss partial ---
// Block: 16 rows x 2048 cols, 16 waves, each wave 16x128 (8 MFMA 16x16x32 tiles).
// Epilogue: direct fragment stores, CACHED (L2 write-combines 64B halves).
__global__ __launch_bounds__(1024) void k_main(
    const f16x8* __restrict__ Ahi, const f16x8* __restrict__ Alo,
    const f16x8* __restrict__ Bhi, const f16x8* __restrict__ Blo,
    const float* __restrict__ cn2g, const float* __restrict__ cbT32,
    float* __restrict__ qout, float* __restrict__ prob,
    float* __restrict__ partials) {
  __shared__ unsigned long long keyS[16];
  __shared__ float rowpart[16][16];
  __shared__ float rowInv[16];
  __shared__ float wsum[16];

  int t = threadIdx.x;
  int lane = t & 63, wv = t >> 6;
  int l15 = lane & 15, g = lane >> 4;
  int rt = blockIdx.x;
  int n0 = rt * 16;
  int wc0 = wv * 128;

  if (t < 16) keyS[t] = ~0ull;

  // A fragments (row = l15, k-chunk = g; s = k-half)
  f16x8 a_hi[2], a_lo[2];
  {
    size_t base = (size_t)rt * 128 + (size_t)g * 16 + l15;
    a_hi[0] = Ahi[base];      a_hi[1] = Ahi[base + 64];
    a_lo[0] = Alo[base];      a_lo[1] = Alo[base + 64];
  }

  f32x4 acc1[8], acc2[8];
  #pragma unroll
  for (int i = 0; i < 8; ++i) {
    acc1[i] = (f32x4){0.f, 0.f, 0.f, 0.f};
    acc2[i] = (f32x4){0.f, 0.f, 0.f, 0.f};
  }

  // B frag index (f16x8 units): s*8192 + t8*64 + (wc0+l15)*4 + g
  int b0 = (wc0 + l15) * 4 + g;
  f16x8 bhA = Bhi[b0], blA = Blo[b0];
  f16x8 bhB, blB;
  #pragma unroll
  for (int p = 0; p < 16; ++p) {  // p = t8*2 + s
    int t8 = p >> 1, s = p & 1;
    if (p < 15) {
      int pn = p + 1;
      int idxn = (pn & 1) * 8192 + (pn >> 1) * 64 + b0;
      if (p & 1) { bhA = Bhi[idxn]; blA = Blo[idxn]; }
      else       { bhB = Bhi[idxn]; blB = Blo[idxn]; }
    }
    f16x8 bh = (p & 1) ? bhB : bhA;
    f16x8 bl = (p & 1) ? blB : blA;
    acc2[t8] = __builtin_amdgcn_mfma_f32_16x16x32_f16(a_lo[s], bh, acc2[t8], 0, 0, 0);
    acc1[t8] = __builtin_amdgcn_mfma_f32_16x16x32_f16(a_hi[s], bh, acc1[t8], 0, 0, 0);
    acc2[t8] = __builtin_amdgcn_mfma_f32_16x16x32_f16(a_hi[s], bl, acc2[t8], 0, 0, 0);
  }

  // Epilogue: d = cn2 - 2*(acc1*2^-16 + acc2*2^-28); exact u64 argmin; e = exp(-d)
  unsigned long long kmin[4] = {~0ull, ~0ull, ~0ull, ~0ull};
  float esum[4] = {0.f, 0.f, 0.f, 0.f};
  #pragma unroll
  for (int t8 = 0; t8 < 8; ++t8) {
    int col = wc0 + t8 * 16 + l15;
    float c2 = cn2g[col];
    #pragma unroll
    for (int r = 0; r < 4; ++r) {
      float dot = fmaf(acc2[t8][r], 3.7252903e-09f, acc1[t8][r] * 1.52587890625e-05f);
      float d = fmaf(-2.0f, dot, c2);
      unsigned long long kk = ((unsigned long long)fkey(d) << 32) | (unsigned)col;
      if (kk < kmin[r]) kmin[r] = kk;
      float e = __expf(-d);
      acc1[t8][r] = e;
      esum[r] += e;
    }
  }
  #pragma unroll
  for (int o = 1; o <= 8; o <<= 1) {  // reduce over 16-lane col group
    #pragma unroll
    for (int r = 0; r < 4; ++r) {
      esum[r] += __shfl_xor(esum[r], o);
      unsigned long long ok = __shfl_xor(kmin[r], o);
      if (ok < kmin[r]) kmin[r] = ok;
    }
  }
  __syncthreads();  // keyS init visible
  if (l15 == 0) {
    #pragma unroll
    for (int r = 0; r < 4; ++r) {
      rowpart[g * 4 + r][wv] = esum[r];
      atomicMin(&keyS[g * 4 + r], kmin[r]);
    }
  }
  __syncthreads();
  if (t < 16) {
    float s = 0.f;
    #pragma unroll
    for (int w = 0; w < 16; ++w) s += rowpart[t][w];
    rowInv[t] = 1.0f / s;
  }
  __syncthreads();

  // prob: direct fragment stores (cached). Wave instr = 4 rows x 64B segments;
  // t8 and t8+1 cover the two halves of each 128B line -> L2 write-combines.
  {
    float4 inv4 = *(const float4*)&rowInv[g * 4];
    float* pp = prob + (size_t)(n0 + g * 4) * KK + wc0 + l15;
    #pragma unroll
    for (int t8 = 0; t8 < 8; ++t8) {
      float* p0 = pp + t8 * 16;
      p0[0]          = acc1[t8][0] * inv4.x;
      p0[KK]         = acc1[t8][1] * inv4.y;
      p0[2 * KK]     = acc1[t8][2] * inv4.z;
      p0[3 * KK]     = acc1[t8][3] * inv4.w;
    }
  }

  // q gather/write + SSD partial (z_norm reconstructed from frags)
  {
    int r = t & 15, k = t >> 4;  // 1024 threads = 16 rows x 64 dims
    int cw = (int)(keyS[r] & 0xffffffffull);
    float qv = cbT32[k * KK + cw];
    int w0 = n0 & 63, hh2 = (n0 >> 6) & 63, bb = n0 >> 12;
    qout[((size_t)((bb << 6) | k) * 64 + hh2) * 64 + w0 + r] = qv;
    size_t aidx = ((size_t)(rt * 2 + (k >> 5)) * 64 + ((k >> 3) & 3) * 16 + r) * 8 + (k & 7);
    float ah = (float)((const _Float16*)Ahi)[aidx];
    float al = (float)((const _Float16*)Alo)[aidx];
    float zn = fmaf(al, 2.44140625e-04f, ah) * 3.90625e-03f;  // (ah + al/4096)/256
    float df = qv - zn;
    float ssd = df * df;
    #pragma unroll
    for (int o = 32; o; o >>= 1) ssd += __shfl_xor(ssd, o);
    if (lane == 0) wsum[wv] = ssd;
  }
  __syncthreads();
  if (t == 0) {
    float s = 0.f;
    #pragma unroll
    for (int w = 0; w < 16; ++w) s += wsum[w];
    partials[rt] = s;
  }
}

// --- K4: deterministic loss reduction ---
__global__ void k_final(const float* __restrict__ partials, float* __restrict__ out) {
  __shared__ float wsh[4];
  int t = threadIdx.x;
  float s = 0.f;
  for (int i = 0; i < 16; ++i) s += partials[t * 16 + i];
  #pragma unroll
  for (int o = 32; o; o >>= 1) s += __shfl_xor(s, o);
  if ((t & 63) == 0) wsh[t >> 6] = s;
  __syncthreads();
  if (t == 0) {
    float tot = (wsh[0] + wsh[1]) + (wsh[2] + wsh[3]);
    float cbl = tot * (1.0f / 4194304.0f);  // mean over n*d
    out[4194304] = 1.25f * cbl;  // loss = cb + 0.25*commit (commit == cb numerically)
    out[4194305] = cbl;
    out[4194306] = cbl;
  }
}

extern "C" void kernel_launch(void* const* d_in, const int* in_sizes, int n_in,
                              void* d_out, int out_size, void* d_ws, size_t ws_size,
                              hipStream_t stream) {
  const float* z = (const float*)d_in[0];
  const float* cb = (const float*)d_in[1];
  float* out = (float*)d_out;
  char* ws = (char*)d_ws;

  float* cbT32 = (float*)(ws);                          // 524288 B
  float* cn2 = (float*)(ws + 524288);                   // 8192 B
  unsigned short* Bhi = (unsigned short*)(ws + 532480); // 262144 B
  unsigned short* Blo = (unsigned short*)(ws + 794624); // 262144 B
  float* partials = (float*)(ws + 1056768);             // 16384 B
  unsigned short* Ahi = (unsigned short*)(ws + 1073152);   // 8 MB
  unsigned short* Alo = (unsigned short*)(ws + 9461760);   // 8 MB

  k_norm_cb<<<512, 256, 0, stream>>>(cb, cbT32, cn2, Bhi, Blo);
  k_norm_z<<<2048, 256, 0, stream>>>(z, Ahi, Alo);
  k_main<<<4096, 1024, 0, stream>>>((const f16x8*)Ahi, (const f16x8*)Alo,
                                    (const f16x8*)Bhi, (const f16x8*)Blo,
                                    cn2, cbT32, out, out + 4194307, partials);
  k_final<<<1, 256, 0, stream>>>(partials, out);
}

// Round 7
// 317.437 us; speedup vs baseline: 1.0340x; 1.0340x over previous
//
#include <hip/hip_runtime.h>

typedef _Float16 f16x8 __attribute__((ext_vector_type(8)));
typedef float f32x4 __attribute__((ext_vector_type(4)));

#define NN 65536
#define KK 2048
#define DD 64

__device__ __forceinline__ unsigned int fkey(float f) {
  unsigned int u = __float_as_uint(f);
  return (u & 0x80000000u) ? ~u : (u | 0x80000000u);
}

// --- K1: normalize codebook -> cbT32[64][2048], cn2[2048], fp16-split frags ---
// cb frag layout (f16 units): idx = s*65536 + c*32 + g2*8 + i  (s=k>>5, g2=(k>>3)&3, i=k&7)
__global__ void k_norm_cb(const float* __restrict__ cb, float* __restrict__ cbT32,
                          float* __restrict__ cn2,
                          unsigned short* __restrict__ Bhi,
                          unsigned short* __restrict__ Blo) {
  int gid = blockIdx.x * blockDim.x + threadIdx.x;
  int c = gid >> 6;   // codebook row, one wave per row
  int k = gid & 63;   // dim
  float v = cb[c * DD + k];
  float ss = v * v;
  #pragma unroll
  for (int o = 32; o; o >>= 1) ss += __shfl_xor(ss, o);
  float inv = 1.0f / fmaxf(sqrtf(ss), 1e-12f);
  float cn = v * inv;
  cbT32[k * KK + c] = cn;
  float s2 = cn * cn;
  #pragma unroll
  for (int o = 32; o; o >>= 1) s2 += __shfl_xor(s2, o);
  if (k == 0) cn2[c] = s2;
  // fp16 split: cn*256 = hh + hl/4096  (both fp16-normal ranged)
  float sh = cn * 256.0f;
  _Float16 hh = (_Float16)sh;
  float resid = sh - (float)hh;
  _Float16 hl = (_Float16)(resid * 4096.0f);
  int s = k >> 5, g2 = (k >> 3) & 3, i = k & 7;
  int idx = s * 65536 + c * 32 + g2 * 8 + i;
  Bhi[idx] = *(unsigned short*)&hh;
  Blo[idx] = *(unsigned short*)&hl;
}

// --- K2: normalize z rows -> fp16-split z frags ---
// z frag layout (f16x8 units): idx = (rt*2+s)*64 + g2*16 + r
__global__ void k_norm_z(const float* __restrict__ z,
                         unsigned short* __restrict__ Ahi,
                         unsigned short* __restrict__ Alo) {
  __shared__ float np_[8][32];
  __shared__ float invS[32];
  int t = threadIdx.x;
  int r32 = t & 31, q = t >> 5;  // row-in-32, k-chunk (8 k each)
  int n0 = blockIdx.x * 32;
  int w0 = n0 & 63, hh = (n0 >> 6) & 63, bb = n0 >> 12;
  const float* src = z + (size_t)bb * 262144 + (size_t)q * 8 * 4096 + hh * 64 + w0 + r32;
  float v[8];
  float ss = 0.f;
  #pragma unroll
  for (int i = 0; i < 8; ++i) {
    float x = src[(size_t)i * 4096];
    v[i] = x;
    ss = fmaf(x, x, ss);
  }
  np_[q][r32] = ss;
  __syncthreads();
  if (t < 32) {
    float s = 0.f;
    #pragma unroll
    for (int qq = 0; qq < 8; ++qq) s += np_[qq][t];
    invS[t] = 1.0f / fmaxf(sqrtf(s), 1e-12f);
  }
  __syncthreads();
  float inv = invS[r32] * 256.0f;
  union { _Float16 h[8]; uint4 u; } hi, lo;
  #pragma unroll
  for (int i = 0; i < 8; ++i) {
    float sh = v[i] * inv;
    _Float16 a = (_Float16)sh;
    hi.h[i] = a;
    lo.h[i] = (_Float16)((sh - (float)a) * 4096.0f);
  }
  int rt = (n0 + r32) >> 4;
  int r = r32 & 15;
  int s = q >> 2, g2 = q & 3;
  size_t idx = (size_t)(rt * 2 + s) * 64 + g2 * 16 + r;
  ((uint4*)Ahi)[idx] = hi.u;
  ((uint4*)Alo)[idx] = lo.u;
}

// --- K3: MFMA GEMM (operand-swapped) + argmin + softmax + prob/q + loss ---
// mfma(cb, z): C col(lane&15) = z-row, row(g*4+r) = code -> each lane's 4 regs
// are 4 CONSECUTIVE CODES of one z-row => direct cached dwordx4 prob stores.
__global__ __launch_bounds__(1024) void k_main(
    const f16x8* __restrict__ Ahi, const f16x8* __restrict__ Alo,
    const f16x8* __restrict__ Bhi, const f16x8* __restrict__ Blo,
    const float* __restrict__ cn2g, const float* __restrict__ cbT32,
    float* __restrict__ qout, float* __restrict__ prob,
    float* __restrict__ partials) {
  __shared__ unsigned long long keyS[16];
  __shared__ float rowpart[16][16];
  __shared__ float rowInv[16];
  __shared__ float wsum[16];

  int t = threadIdx.x;
  int lane = t & 63, wv = t >> 6;
  int l15 = lane & 15, g = lane >> 4;
  int rt = blockIdx.x;
  int n0 = rt * 16;
  int wc0 = wv * 128;

  if (t < 16) keyS[t] = ~0ull;

  // z fragments (B-operand now): z-row = l15, k-chunk = g, half = s
  f16x8 z_hi[2], z_lo[2];
  {
    size_t base = (size_t)rt * 128 + (size_t)g * 16 + l15;
    z_hi[0] = Ahi[base];      z_hi[1] = Ahi[base + 64];
    z_lo[0] = Alo[base];      z_lo[1] = Alo[base + 64];
  }

  f32x4 acc1[8], acc2[8];
  #pragma unroll
  for (int i = 0; i < 8; ++i) {
    acc1[i] = (f32x4){0.f, 0.f, 0.f, 0.f};
    acc2[i] = (f32x4){0.f, 0.f, 0.f, 0.f};
  }

  // cb frag stream (A-operand now): code = wc0+t8*16+l15, idx = s*8192 + t8*64 + (wc0+l15)*4 + g
  int b0 = (wc0 + l15) * 4 + g;
  f16x8 bhA = Bhi[b0], blA = Blo[b0];
  f16x8 bhB, blB;
  #pragma unroll
  for (int p = 0; p < 16; ++p) {  // p = t8*2 + s
    int t8 = p >> 1, s = p & 1;
    if (p < 15) {
      int pn = p + 1;
      int idxn = (pn & 1) * 8192 + (pn >> 1) * 64 + b0;
      if (p & 1) { bhA = Bhi[idxn]; blA = Blo[idxn]; }
      else       { bhB = Bhi[idxn]; blB = Blo[idxn]; }
    }
    f16x8 bh = (p & 1) ? bhB : bhA;  // cb_hi
    f16x8 bl = (p & 1) ? blB : blA;  // cb_lo
    acc2[t8] = __builtin_amdgcn_mfma_f32_16x16x32_f16(bh, z_lo[s], acc2[t8], 0, 0, 0);
    acc1[t8] = __builtin_amdgcn_mfma_f32_16x16x32_f16(bh, z_hi[s], acc1[t8], 0, 0, 0);
    acc2[t8] = __builtin_amdgcn_mfma_f32_16x16x32_f16(bl, z_hi[s], acc2[t8], 0, 0, 0);
  }

  // Epilogue: d = cn2 - 2*(acc1*2^-16 + acc2*2^-28); exact u64 argmin; e = exp(-d)
  // Each thread: ONE z-row (l15), 32 codes {wc0 + t8*16 + g*4 + r}.
  unsigned long long kmin = ~0ull;
  float esum = 0.f;
  int cb0 = wc0 + g * 4;
  #pragma unroll
  for (int t8 = 0; t8 < 8; ++t8) {
    int c0 = cb0 + t8 * 16;
    float4 c4 = *(const float4*)(cn2g + c0);
    float cn[4] = {c4.x, c4.y, c4.z, c4.w};
    #pragma unroll
    for (int r = 0; r < 4; ++r) {
      float dot = fmaf(acc2[t8][r], 3.7252903e-09f, acc1[t8][r] * 1.52587890625e-05f);
      float d = fmaf(-2.0f, dot, cn[r]);
      unsigned long long kk = ((unsigned long long)fkey(d) << 32) | (unsigned)(c0 + r);
      if (kk < kmin) kmin = kk;
      float e = __expf(-d);
      acc1[t8][r] = e;
      esum += e;
    }
  }
  // combine the 4 g-groups sharing one z-row (lanes l15, l15+16, +32, +48)
  #pragma unroll
  for (int o = 16; o <= 32; o <<= 1) {
    esum += __shfl_xor(esum, o);
    unsigned long long ok = __shfl_xor(kmin, o);
    if (ok < kmin) kmin = ok;
  }
  __syncthreads();  // keyS init visible
  if (lane < 16) {
    rowpart[l15][wv] = esum;
    atomicMin(&keyS[l15], kmin);
  }
  __syncthreads();
  if (t < 16) {
    float s = 0.f;
    #pragma unroll
    for (int w = 0; w < 16; ++w) s += rowpart[t][w];
    rowInv[t] = 1.0f / s;
  }
  __syncthreads();

  // prob: direct cached dwordx4 stores from fragments (4 consecutive codes/lane)
  {
    float inv = rowInv[l15];
    float* pp = prob + (size_t)(n0 + l15) * KK + cb0;
    #pragma unroll
    for (int t8 = 0; t8 < 8; ++t8) {
      f32x4 o4 = acc1[t8] * inv;
      *(f32x4*)(pp + t8 * 16) = o4;
    }
  }

  // q gather/write + SSD partial (z_norm reconstructed from frags)
  {
    int r = t & 15, k = t >> 4;  // 1024 threads = 16 rows x 64 dims
    int cw = (int)(keyS[r] & 0xffffffffull);
    float qv = cbT32[k * KK + cw];
    int w0 = n0 & 63, hh2 = (n0 >> 6) & 63, bb = n0 >> 12;
    qout[((size_t)((bb << 6) | k) * 64 + hh2) * 64 + w0 + r] = qv;
    size_t aidx = ((size_t)(rt * 2 + (k >> 5)) * 64 + ((k >> 3) & 3) * 16 + r) * 8 + (k & 7);
    float ah = (float)((const _Float16*)Ahi)[aidx];
    float al = (float)((const _Float16*)Alo)[aidx];
    float zn = fmaf(al, 2.44140625e-04f, ah) * 3.90625e-03f;  // (ah + al/4096)/256
    float df = qv - zn;
    float ssd = df * df;
    #pragma unroll
    for (int o = 32; o; o >>= 1) ssd += __shfl_xor(ssd, o);
    if (lane == 0) wsum[wv] = ssd;
  }
  __syncthreads();
  if (t == 0) {
    float s = 0.f;
    #pragma unroll
    for (int w = 0; w < 16; ++w) s += wsum[w];
    partials[rt] = s;
  }
}

// --- K4: deterministic loss reduction ---
__global__ void k_final(const float* __restrict__ partials, float* __restrict__ out) {
  __shared__ float wsh[4];
  int t = threadIdx.x;
  float s = 0.f;
  for (int i = 0; i < 16; ++i) s += partials[t * 16 + i];
  #pragma unroll
  for (int o = 32; o; o >>= 1) s += __shfl_xor(s, o);
  if ((t & 63) == 0) wsh[t >> 6] = s;
  __syncthreads();
  if (t == 0) {
    float tot = (wsh[0] + wsh[1]) + (wsh[2] + wsh[3]);
    float cbl = tot * (1.0f / 4194304.0f);  // mean over n*d
    out[4194304] = 1.25f * cbl;  // loss = cb + 0.25*commit (commit == cb numerically)
    out[4194305] = cbl;
    out[4194306] = cbl;
  }
}

extern "C" void kernel_launch(void* const* d_in, const int* in_sizes, int n_in,
                              void* d_out, int out_size, void* d_ws, size_t ws_size,
                              hipStream_t stream) {
  const float* z = (const float*)d_in[0];
  const float* cb = (const float*)d_in[1];
  float* out = (float*)d_out;
  char* ws = (char*)d_ws;

  float* cbT32 = (float*)(ws);                          // 524288 B
  float* cn2 = (float*)(ws + 524288);                   // 8192 B
  unsigned short* Bhi = (unsigned short*)(ws + 532480); // 262144 B
  unsigned short* Blo = (unsigned short*)(ws + 794624); // 262144 B
  float* partials = (float*)(ws + 1056768);             // 16384 B
  unsigned short* Ahi = (unsigned short*)(ws + 1073152);   // 8 MB
  unsigned short* Alo = (unsigned short*)(ws + 9461760);   // 8 MB

  k_norm_cb<<<512, 256, 0, stream>>>(cb, cbT32, cn2, Bhi, Blo);
  k_norm_z<<<2048, 256, 0, stream>>>(z, Ahi, Alo);
  k_main<<<4096, 1024, 0, stream>>>((const f16x8*)Ahi, (const f16x8*)Alo,
                                    (const f16x8*)Bhi, (const f16x8*)Blo,
                                    cn2, cbT32, out, out + 4194307, partials);
  k_final<<<1, 256, 0, stream>>>(partials, out);
}

// Round 8
// 289.867 us; speedup vs baseline: 1.1323x; 1.0951x over previous
//
#include <hip/hip_runtime.h>
#include <hip/hip_fp16.h>

typedef _Float16 f16x8 __attribute__((ext_vector_type(8)));
typedef float f32x4 __attribute__((ext_vector_type(4)));

#define NN 65536
#define KK 2048
#define DD 64

__device__ __forceinline__ unsigned int fkey(float f) {
  unsigned int u = __float_as_uint(f);
  return (u & 0x80000000u) ? ~u : (u | 0x80000000u);
}

// --- K1: normalize codebook -> cbT32[64][2048], cn2[2048], fp16-split frags ---
// cb frag layout (f16 units): idx = s*65536 + c*32 + g2*8 + i  (s=k>>5, g2=(k>>3)&3, i=k&7)
__global__ void k_norm_cb(const float* __restrict__ cb, float* __restrict__ cbT32,
                          float* __restrict__ cn2,
                          unsigned short* __restrict__ Bhi,
                          unsigned short* __restrict__ Blo) {
  int gid = blockIdx.x * blockDim.x + threadIdx.x;
  int c = gid >> 6;   // codebook row, one wave per row
  int k = gid & 63;   // dim
  float v = cb[c * DD + k];
  float ss = v * v;
  #pragma unroll
  for (int o = 32; o; o >>= 1) ss += __shfl_xor(ss, o);
  float inv = 1.0f / fmaxf(sqrtf(ss), 1e-12f);
  float cn = v * inv;
  cbT32[k * KK + c] = cn;
  float s2 = cn * cn;
  #pragma unroll
  for (int o = 32; o; o >>= 1) s2 += __shfl_xor(s2, o);
  if (k == 0) cn2[c] = s2;
  // fp16 split: cn*256 = hh + hl/4096  (both fp16-normal ranged)
  float sh = cn * 256.0f;
  _Float16 hh = (_Float16)sh;
  float resid = sh - (float)hh;
  _Float16 hl = (_Float16)(resid * 4096.0f);
  int s = k >> 5, g2 = (k >> 3) & 3, i = k & 7;
  int idx = s * 65536 + c * 32 + g2 * 8 + i;
  Bhi[idx] = *(unsigned short*)&hh;
  Blo[idx] = *(unsigned short*)&hl;
}

// --- K2: normalize z rows -> fp16-split z frags ---
// z frag layout (f16x8 units): idx = (rt*2+s)*64 + g2*16 + r
__global__ void k_norm_z(const float* __restrict__ z,
                         unsigned short* __restrict__ Ahi,
                         unsigned short* __restrict__ Alo) {
  __shared__ float np_[8][32];
  __shared__ float invS[32];
  int t = threadIdx.x;
  int r32 = t & 31, q = t >> 5;  // row-in-32, k-chunk (8 k each)
  int n0 = blockIdx.x * 32;
  int w0 = n0 & 63, hh = (n0 >> 6) & 63, bb = n0 >> 12;
  const float* src = z + (size_t)bb * 262144 + (size_t)q * 8 * 4096 + hh * 64 + w0 + r32;
  float v[8];
  float ss = 0.f;
  #pragma unroll
  for (int i = 0; i < 8; ++i) {
    float x = src[(size_t)i * 4096];
    v[i] = x;
    ss = fmaf(x, x, ss);
  }
  np_[q][r32] = ss;
  __syncthreads();
  if (t < 32) {
    float s = 0.f;
    #pragma unroll
    for (int qq = 0; qq < 8; ++qq) s += np_[qq][t];
    invS[t] = 1.0f / fmaxf(sqrtf(s), 1e-12f);
  }
  __syncthreads();
  float inv = invS[r32] * 256.0f;
  union { _Float16 h[8]; uint4 u; } hi, lo;
  #pragma unroll
  for (int i = 0; i < 8; ++i) {
    float sh = v[i] * inv;
    _Float16 a = (_Float16)sh;
    hi.h[i] = a;
    lo.h[i] = (_Float16)((sh - (float)a) * 4096.0f);
  }
  int rt = (n0 + r32) >> 4;
  int r = r32 & 15;
  int s = q >> 2, g2 = q & 3;
  size_t idx = (size_t)(rt * 2 + s) * 64 + g2 * 16 + r;
  ((uint4*)Ahi)[idx] = hi.u;
  ((uint4*)Alo)[idx] = lo.u;
}

// --- K3: MFMA GEMM (operand-swapped) + argmin + softmax + prob/q + loss ---
// 512 threads / 8 waves; 16 rows x 2048 cols via TWO col-half passes.
// Pass-0 e parked in LDS (fp16); acc2 folded per-tile -> ~96 VGPR -> 2 blocks/CU
// so one block's K-loop overlaps the other's store burst.
__global__ __launch_bounds__(512, 4) void k_main(
    const f16x8* __restrict__ Ahi, const f16x8* __restrict__ Alo,
    const f16x8* __restrict__ Bhi, const f16x8* __restrict__ Blo,
    const float* __restrict__ cn2g, const float* __restrict__ cbT32,
    float* __restrict__ qout, float* __restrict__ prob,
    float* __restrict__ partials) {
  __shared__ __half ehS[16][1032];  // pass-0 e (fp16), padded stride vs bank conflicts
  __shared__ unsigned long long keyS[16];
  __shared__ float rowpart[16][8];
  __shared__ float rowInv[16];
  __shared__ float wsum[8];

  int t = threadIdx.x;
  int lane = t & 63, wv = t >> 6;  // wv 0..7
  int l15 = lane & 15, g = lane >> 4;
  int rt = blockIdx.x;
  int n0 = rt * 16;

  if (t < 16) keyS[t] = ~0ull;

  // z fragments (B-operand): z-row = l15, k-chunk = g, half = s
  f16x8 z_hi[2], z_lo[2];
  {
    size_t base = (size_t)rt * 128 + (size_t)g * 16 + l15;
    z_hi[0] = Ahi[base];      z_hi[1] = Ahi[base + 64];
    z_lo[0] = Alo[base];      z_lo[1] = Alo[base + 64];
  }

  f32x4 acc1[8];
  unsigned long long kmin = ~0ull;
  float esumT = 0.f;

  #pragma unroll
  for (int pass = 0; pass < 2; ++pass) {
    int wc0 = pass * 1024 + wv * 128;
    #pragma unroll
    for (int i = 0; i < 8; ++i) acc1[i] = (f32x4){0.f, 0.f, 0.f, 0.f};
    f32x4 acc2t = (f32x4){0.f, 0.f, 0.f, 0.f};

    // cb frag stream (A-operand): idx(f16x8) = s*8192 + t8*64 + (wc0+l15)*4 + g
    int b0 = (wc0 + l15) * 4 + g;
    f16x8 bhA = Bhi[b0], blA = Blo[b0];
    f16x8 bhB, blB;
    #pragma unroll
    for (int p = 0; p < 16; ++p) {  // p = t8*2 + s
      int t8 = p >> 1, s = p & 1;
      if (p < 15) {
        int pn = p + 1;
        int idxn = (pn & 1) * 8192 + (pn >> 1) * 64 + b0;
        if (p & 1) { bhA = Bhi[idxn]; blA = Blo[idxn]; }
        else       { bhB = Bhi[idxn]; blB = Blo[idxn]; }
      }
      f16x8 bh = (p & 1) ? bhB : bhA;  // cb_hi
      f16x8 bl = (p & 1) ? blB : blA;  // cb_lo
      acc2t    = __builtin_amdgcn_mfma_f32_16x16x32_f16(bh, z_lo[s], acc2t, 0, 0, 0);
      acc1[t8] = __builtin_amdgcn_mfma_f32_16x16x32_f16(bh, z_hi[s], acc1[t8], 0, 0, 0);
      acc2t    = __builtin_amdgcn_mfma_f32_16x16x32_f16(bl, z_hi[s], acc2t, 0, 0, 0);
      if (s == 1) {  // tile complete: fold low-order correction (== acc2*2^-28 path)
        acc1[t8] += acc2t * 2.44140625e-04f;  // 2^-12
        acc2t = (f32x4){0.f, 0.f, 0.f, 0.f};
      }
    }

    // per-pass epilogue: d = cn2 - 2*acc1*2^-16; exact u64 argmin; e = exp(-d)
    int cb0 = wc0 + g * 4;
    #pragma unroll
    for (int t8 = 0; t8 < 8; ++t8) {
      int c0 = cb0 + t8 * 16;
      float4 c4 = *(const float4*)(cn2g + c0);
      float cn[4] = {c4.x, c4.y, c4.z, c4.w};
      #pragma unroll
      for (int r = 0; r < 4; ++r) {
        float d = fmaf(acc1[t8][r], -3.0517578125e-05f, cn[r]);  // -2*2^-16
        unsigned long long kk = ((unsigned long long)fkey(d) << 32) | (unsigned)(c0 + r);
        if (kk < kmin) kmin = kk;
        float e = __expf(-d);
        acc1[t8][r] = e;
        esumT += e;
      }
    }
    if (pass == 0) {  // park e in LDS as fp16 (same thread reads it back later)
      #pragma unroll
      for (int t8 = 0; t8 < 8; ++t8) {
        int off = wv * 128 + t8 * 16 + g * 4;
        *(__half2*)&ehS[l15][off]     = __floats2half2_rn(acc1[t8][0], acc1[t8][1]);
        *(__half2*)&ehS[l15][off + 2] = __floats2half2_rn(acc1[t8][2], acc1[t8][3]);
      }
    }
  }

  // combine 4 g-groups sharing one z-row (lanes l15, +16, +32, +48)
  #pragma unroll
  for (int o = 16; o <= 32; o <<= 1) {
    esumT += __shfl_xor(esumT, o);
    unsigned long long ok = __shfl_xor(kmin, o);
    if (ok < kmin) kmin = ok;
  }
  __syncthreads();  // keyS init visible
  if (lane < 16) {
    rowpart[l15][wv] = esumT;
    atomicMin(&keyS[l15], kmin);
  }
  __syncthreads();
  if (t < 16) {
    float s = 0.f;
    #pragma unroll
    for (int w = 0; w < 8; ++w) s += rowpart[t][w];
    rowInv[t] = 1.0f / s;
  }
  __syncthreads();

  // prob stores: pass-1 from regs, pass-0 from LDS (dwordx4 each)
  {
    float inv = rowInv[l15];
    float* pr = prob + (size_t)(n0 + l15) * KK + wv * 128 + g * 4;
    #pragma unroll
    for (int t8 = 0; t8 < 8; ++t8)
      *(f32x4*)(pr + 1024 + t8 * 16) = acc1[t8] * inv;
    #pragma unroll
    for (int t8 = 0; t8 < 8; ++t8) {
      int off = wv * 128 + t8 * 16 + g * 4;
      __half2 a = *(__half2*)&ehS[l15][off];
      __half2 b = *(__half2*)&ehS[l15][off + 2];
      f32x4 o4;
      o4[0] = __low2float(a) * inv;
      o4[1] = __high2float(a) * inv;
      o4[2] = __low2float(b) * inv;
      o4[3] = __high2float(b) * inv;
      *(f32x4*)(pr + t8 * 16) = o4;
    }
  }

  // q gather/write + SSD partial (z_norm reconstructed from frags)
  {
    float ssd = 0.f;
    #pragma unroll
    for (int i = 0; i < 2; ++i) {
      int e = i * 512 + t;       // 0..1023 over (d, wi)
      int d = e >> 4, wi = e & 15;
      int cw = (int)(keyS[wi] & 0xffffffffull);
      float qv = cbT32[d * KK + cw];
      int w0 = n0 & 63, hh2 = (n0 >> 6) & 63, bb = n0 >> 12;
      qout[((size_t)((bb << 6) | d) * 64 + hh2) * 64 + w0 + wi] = qv;
      size_t aidx = ((size_t)(rt * 2 + (d >> 5)) * 64 + ((d >> 3) & 3) * 16 + wi) * 8 + (d & 7);
      float ah = (float)((const _Float16*)Ahi)[aidx];
      float al = (float)((const _Float16*)Alo)[aidx];
      float zn = fmaf(al, 2.44140625e-04f, ah) * 3.90625e-03f;  // (ah + al/4096)/256
      float df = qv - zn;
      ssd = fmaf(df, df, ssd);
    }
    #pragma unroll
    for (int o = 32; o; o >>= 1) ssd += __shfl_xor(ssd, o);
    if (lane == 0) wsum[wv] = ssd;
  }
  __syncthreads();
  if (t == 0) {
    float s = 0.f;
    #pragma unroll
    for (int w = 0; w < 8; ++w) s += wsum[w];
    partials[rt] = s;
  }
}

// --- K4: deterministic loss reduction ---
__global__ void k_final(const float* __restrict__ partials, float* __restrict__ out) {
  __shared__ float wsh[4];
  int t = threadIdx.x;
  float s = 0.f;
  for (int i = 0; i < 16; ++i) s += partials[t * 16 + i];
  #pragma unroll
  for (int o = 32; o; o >>= 1) s += __shfl_xor(s, o);
  if ((t & 63) == 0) wsh[t >> 6] = s;
  __syncthreads();
  if (t == 0) {
    float tot = (wsh[0] + wsh[1]) + (wsh[2] + wsh[3]);
    float cbl = tot * (1.0f / 4194304.0f);  // mean over n*d
    out[4194304] = 1.25f * cbl;  // loss = cb + 0.25*commit (commit == cb numerically)
    out[4194305] = cbl;
    out[4194306] = cbl;
  }
}

extern "C" void kernel_launch(void* const* d_in, const int* in_sizes, int n_in,
                              void* d_out, int out_size, void* d_ws, size_t ws_size,
                              hipStream_t stream) {
  const float* z = (const float*)d_in[0];
  const float* cb = (const float*)d_in[1];
  float* out = (float*)d_out;
  char* ws = (char*)d_ws;

  float* cbT32 = (float*)(ws);                          // 524288 B
  float* cn2 = (float*)(ws + 524288);                   // 8192 B
  unsigned short* Bhi = (unsigned short*)(ws + 532480); // 262144 B
  unsigned short* Blo = (unsigned short*)(ws + 794624); // 262144 B
  float* partials = (float*)(ws + 1056768);             // 16384 B
  unsigned short* Ahi = (unsigned short*)(ws + 1073152);   // 8 MB
  unsigned short* Alo = (unsigned short*)(ws + 9461760);   // 8 MB

  k_norm_cb<<<512, 256, 0, stream>>>(cb, cbT32, cn2, Bhi, Blo);
  k_norm_z<<<2048, 256, 0, stream>>>(z, Ahi, Alo);
  k_main<<<4096, 512, 0, stream>>>((const f16x8*)Ahi, (const f16x8*)Alo,
                                   (const f16x8*)Bhi, (const f16x8*)Blo,
                                   cn2, cbT32, out, out + 4194307, partials);
  k_final<<<1, 256, 0, stream>>>(partials, out);
}